// Round 7
// baseline (400.217 us; speedup 1.0000x reference)
//
#include <hip/hip_runtime.h>

// WKV7 (RWKV-7) forward scan. T=2048, H=64, D=64.
// R7: lookahead expansion removes the 16-lane reduction from the carried
// dependency cycle:
//   sa_{t+1} = R2 + beta*sa_t + gamma*v_t,  where
//   R2    = sum_j S_{t-1}[i,j] * e_t[j] * a_{t+1}[j]   (reduce, full-body slack)
//   beta  = b_t . a_{t+1}                               (inputs only)
//   gamma = k_t . a_{t+1}                               (inputs only)
// Carried chain is now 2 fma per step. Needs a_{t+1} at body top -> 3-deep
// register buffers (cur/nx1/nx2), vmcnt(30) guarantees stage t+2 resident.
// Also: y-store restricted to 4 lanes (was 16x same-address duplication).

typedef float f32x4 __attribute__((ext_vector_type(4)));

constexpr int T_LEN = 2048;
constexpr int DD    = 64;
constexpr int HD    = 64 * 64;   // 4096

#define AS1 __attribute__((address_space(1)))
#define AS3 __attribute__((address_space(3)))

struct Buf { f32x4 r, e, k, a, b; float vv; };

__global__ __launch_bounds__(256)
void exp_kernel(const float4* __restrict__ w, float4* __restrict__ ew, int n4) {
  int i = blockIdx.x * blockDim.x + threadIdx.x;
  int stride = gridDim.x * blockDim.x;
  for (; i < n4; i += stride) {
    float4 x = w[i];
    float4 o;
    o.x = __expf(x.x); o.y = __expf(x.y); o.z = __expf(x.z); o.w = __expf(x.w);
    ew[i] = o;
  }
}

template<int CTRL>
__device__ __forceinline__ float dpp_add(float x) {
  int y = __builtin_amdgcn_update_dpp(0, __float_as_int(x), CTRL, 0xf, 0xf, true);
  return x + __int_as_float(y);
}

// Sum across the 16 lanes of a DPP row (all lanes end with the sum).
__device__ __forceinline__ float row16_reduce(float x) {
  x = dpp_add<0xB1>(x);    // quad_perm [1,0,3,2] : + lane^1
  x = dpp_add<0x4E>(x);    // quad_perm [2,3,0,1] : + lane^2
  x = dpp_add<0x141>(x);   // row_half_mirror    : + other quad
  x = dpp_add<0x140>(x);   // row_mirror         : + other half
  return x;
}

__device__ __forceinline__ float dot4(const f32x4& x, const f32x4& y) {
  return fmaf(x[3], y[3], fmaf(x[2], y[2], fmaf(x[1], y[1], x[0] * y[0])));
}

__device__ __forceinline__ void gload_lds(const float* g, const float* l) {
  __builtin_amdgcn_global_load_lds((const AS1 unsigned*)g, (AS3 unsigned*)l, 4, 0, 0);
}

__global__ __launch_bounds__(64, 1)
void wkv7_scan(const float* __restrict__ R, const float* __restrict__ EW,
               const float* __restrict__ K, const float* __restrict__ V,
               const float* __restrict__ A, const float* __restrict__ B,
               const float* __restrict__ S0, float* __restrict__ X,
               float* __restrict__ SOUT)
{
  // 8 slots x (5 vectors + v) x 64 floats = 3072 floats = 12 KB
  __shared__ float smem[3072];

  const int blk = blockIdx.x;          // 0..1023
  // XCD co-location: 8 whole heads (16 row-blocks each) per XCD for L2 reuse.
  const int xcd = blk & 7;
  const int m   = blk >> 3;            // 0..127
  const int h   = xcd * 8 + (m & 7);   // head 0..63
  const int br  = m >> 3;              // row block 0..15

  const int lane = threadIdx.x;        // 0..63
  const int cg   = lane & 15;          // cols [cg*4, cg*4+4)
  const int rl   = lane >> 4;          // local row 0..3
  const int row  = br * 4 + rl;        // 0..63
  const int c0   = cg * 4;

  const int laneoff = h * DD + lane;   // per-lane global offset, all 6 arrays

  const unsigned lb  = (unsigned)(uintptr_t)(AS3 float*)&smem[0];
  const unsigned vab = lb + (unsigned)(cg * 16);   // vector-read base
  const unsigned vvb = lb + (unsigned)(row * 4);   // v-read base (offset:1280)

  int yoff = (h * DD + row) * 4;       // byte offset into X, advances by HD*4

  f32x4 s;
  {
    const f32x4* sp = (const f32x4*)(S0 + (size_t)h * DD * DD + row * DD + c0);
    s = *sp;
  }

  auto stage = [&](int tt, int slot) {
    const size_t o = (size_t)tt * HD + laneoff;
    const float* l = &smem[slot * 384];
    gload_lds(R  + o, l);
    gload_lds(EW + o, l + 64);
    gload_lds(K  + o, l + 128);
    gload_lds(A  + o, l + 192);
    gload_lds(B  + o, l + 256);
    gload_lds(V  + o, l + 320);
  };

  auto lds_read = [&](Buf& d, int slot) {
    unsigned va = vab + (unsigned)(slot * 1536);
    unsigned vv = vvb + (unsigned)(slot * 1536);
    asm volatile(
      "ds_read_b128 %0, %6\n\t"
      "ds_read_b128 %1, %6 offset:256\n\t"
      "ds_read_b128 %2, %6 offset:512\n\t"
      "ds_read_b128 %3, %6 offset:768\n\t"
      "ds_read_b128 %4, %6 offset:1024\n\t"
      "ds_read_b32  %5, %7 offset:1280"
      : "=&v"(d.r), "=&v"(d.e), "=&v"(d.k), "=&v"(d.a), "=&v"(d.b), "=&v"(d.vv)
      : "v"(va), "v"(vv) : "memory");
  };

  // Wait for nx1's ds_reads (issued last body; only the 6 just issued for nx2
  // are newer). Tied to nx1's registers as a data dependency: consumers of
  // nx1 (and, transitively, next body's cur-uses) order after the wait;
  // independent VALU floats freely.
  auto wait_nx1 = [&](Buf& d) {
    asm volatile("s_waitcnt lgkmcnt(6)"
                 : "+v"(d.r), "+v"(d.e), "+v"(d.k), "+v"(d.a), "+v"(d.b),
                   "+v"(d.vv));
  };

  float sa;  // carried per-row scalar: sa_t = S_{t-1} . a_t

  auto body = [&](Buf& cur, Buf& nx1, Buf& nx2, int t) {
    // Guarantee stage t+2 resident: steady-state, ops newer than its last
    // load = 5 bodies x (1 store + 6 loads) = 35; use 30 (covers ramp-up
    // bodies too, slightly conservative in steady state).
    asm volatile("s_waitcnt vmcnt(30)" ::: "memory");
    lds_read(nx2, (t + 2) & 7);
    wait_nx1(nx1);

    // ---- lookahead pieces for step t+1 (use PRE-update s) ----
    f32x4 q;
    q[0] = cur.e[0] * nx1.a[0];
    q[1] = cur.e[1] * nx1.a[1];
    q[2] = cur.e[2] * nx1.a[2];
    q[3] = cur.e[3] * nx1.a[3];
    float R2    = row16_reduce(dot4(s, q));
    float beta  = row16_reduce(dot4(cur.b, nx1.a));
    float gamma = row16_reduce(dot4(cur.k, nx1.a));

    // ---- state update for step t (sa is ready from last body) ----
    const float vv = cur.vv;
    s[0] = fmaf(cur.e[0], s[0], fmaf(sa, cur.b[0], vv * cur.k[0]));
    s[1] = fmaf(cur.e[1], s[1], fmaf(sa, cur.b[1], vv * cur.k[1]));
    s[2] = fmaf(cur.e[2], s[2], fmaf(sa, cur.b[2], vv * cur.k[2]));
    s[3] = fmaf(cur.e[3], s[3], fmaf(sa, cur.b[3], vv * cur.k[3]));

    // ---- output (off the carried chain) ----
    float y0 = fmaf(s[2], cur.r[2], s[0] * cur.r[0]);
    float y1 = fmaf(s[3], cur.r[3], s[1] * cur.r[1]);
    float y  = row16_reduce(y0 + y1);
    if (cg == 0) {   // one lane per row group: 4 lanes, 16B coalesced
      asm volatile("global_store_dword %0, %1, %2"
                   :: "v"(yoff), "v"(y), "s"(X) : "memory");
    }
    yoff += HD * 4;

    // ---- carried chain: 2 fma ----
    sa = fmaf(beta, sa, fmaf(gamma, vv, R2));

    stage((t + 8) & (T_LEN - 1), t & 7);  // refill freed slot
  };

  // Prologue: fill the ring (stages 0..7, issue order = count order).
  for (int i = 0; i < 8; ++i) {
    stage(i, i);
    __builtin_amdgcn_sched_barrier(0);
  }
  // Stages 0 and 1 done: 36 loads (stages 2..7) are newer than stage 1.
  asm volatile("s_waitcnt vmcnt(36)" ::: "memory");

  Buf B0, B1, B2, B3;
  lds_read(B0, 0);
  lds_read(B1, 1);
  asm volatile("s_waitcnt lgkmcnt(0)"
               : "+v"(B0.r), "+v"(B0.e), "+v"(B0.k), "+v"(B0.a), "+v"(B0.b),
                 "+v"(B0.vv), "+v"(B1.a));

  // sa_0 = S_init . a_0 (direct; only prologue pays the reduce latency)
  sa = row16_reduce(dot4(s, B0.a));

  for (int t = 0; t < T_LEN; t += 4) {
    body(B0, B1, B2, t);
    body(B1, B2, B3, t + 1);
    body(B2, B3, B0, t + 2);
    body(B3, B0, B1, t + 3);
  }

  *(f32x4*)(SOUT + (size_t)h * DD * DD + row * DD + c0) = s;
}

extern "C" void kernel_launch(void* const* d_in, const int* in_sizes, int n_in,
                              void* d_out, int out_size, void* d_ws, size_t ws_size,
                              hipStream_t stream) {
  // setup_inputs order: seq_length, r, w, k, v, a, b, state2
  const float* r  = (const float*)d_in[1];
  const float* w  = (const float*)d_in[2];
  const float* k  = (const float*)d_in[3];
  const float* v  = (const float*)d_in[4];
  const float* a  = (const float*)d_in[5];
  const float* b  = (const float*)d_in[6];
  const float* s0 = (const float*)d_in[7];

  float* x    = (float*)d_out;                     // (T, H, 1, D)
  float* sout = x + (size_t)T_LEN * HD;            // (H, D, D)

  float* ew = (float*)d_ws;
  (void)ws_size; (void)in_sizes; (void)n_in;

  int n4 = T_LEN * HD / 4;
  hipLaunchKernelGGL(exp_kernel, dim3(1024), dim3(256), 0, stream,
                     (const float4*)w, (float4*)ew, n4);
  hipLaunchKernelGGL(wkv7_scan, dim3(1024), dim3(64), 0, stream,
                     r, ew, k, v, a, b, s0, x, sout);
}

// Round 9
// 360.052 us; speedup vs baseline: 1.1116x; 1.1116x over previous
//
#include <hip/hip_runtime.h>

// WKV7 (RWKV-7) forward scan. T=2048, H=64, D=64.
// R9 = R8 + DPP hazard fix. R8's duo_reduce read its inputs with
// v_mov_b32_dpp ZERO instructions after the producing fma (asm entry
// boundary) — CDNA requires 2 wait states between a VALU write and a DPP
// read of that register. s_nop 1 at block entry provides them.
// Structure (from R8): 8-slot global_load_lds ring, 3-deep reg buffers,
// state update consumes sa computed LAST body, both dots reduced in one
// interleaved DPP block, y-store pipelined one body later.

typedef float f32x4 __attribute__((ext_vector_type(4)));

constexpr int T_LEN = 2048;
constexpr int DD    = 64;
constexpr int HD    = 64 * 64;   // 4096

#define AS1 __attribute__((address_space(1)))
#define AS3 __attribute__((address_space(3)))

struct Buf { f32x4 r, e, k, a, b; float vv; };

__global__ __launch_bounds__(256)
void exp_kernel(const float4* __restrict__ w, float4* __restrict__ ew, int n4) {
  int i = blockIdx.x * blockDim.x + threadIdx.x;
  int stride = gridDim.x * blockDim.x;
  for (; i < n4; i += stride) {
    float4 x = w[i];
    float4 o;
    o.x = __expf(x.x); o.y = __expf(x.y); o.z = __expf(x.z); o.w = __expf(x.w);
    ew[i] = o;
  }
}

template<int CTRL>
__device__ __forceinline__ float dpp_add(float x) {
  int y = __builtin_amdgcn_update_dpp(0, __float_as_int(x), CTRL, 0xf, 0xf, true);
  return x + __int_as_float(y);
}

// Sum across 16 lanes (prologue only; compiler handles hazards for builtins).
__device__ __forceinline__ float row16_reduce(float x) {
  x = dpp_add<0xB1>(x);    // quad_perm [1,0,3,2]
  x = dpp_add<0x4E>(x);    // quad_perm [2,3,0,1]
  x = dpp_add<0x141>(x);   // row_half_mirror
  x = dpp_add<0x140>(x);   // row_mirror
  return x;
}

// Two row-of-16 reductions, DPP levels interleaved; dependent ops >=2 wait
// states apart. s_nop 1 at ENTRY covers the external producer->first-DPP
// hazard (the R8 bug).
__device__ __forceinline__ void duo_reduce(float& a, float& b) {
  float t0, t1;
  asm volatile(
    "s_nop 1\n\t"
    "v_mov_b32_dpp %2, %0 quad_perm:[1,0,3,2] row_mask:0xf bank_mask:0xf\n\t"
    "v_mov_b32_dpp %3, %1 quad_perm:[1,0,3,2] row_mask:0xf bank_mask:0xf\n\t"
    "s_nop 0\n\t"
    "v_add_f32 %0, %0, %2\n\t"
    "v_add_f32 %1, %1, %3\n\t"
    "s_nop 0\n\t"
    "v_mov_b32_dpp %2, %0 quad_perm:[2,3,0,1] row_mask:0xf bank_mask:0xf\n\t"
    "v_mov_b32_dpp %3, %1 quad_perm:[2,3,0,1] row_mask:0xf bank_mask:0xf\n\t"
    "s_nop 0\n\t"
    "v_add_f32 %0, %0, %2\n\t"
    "v_add_f32 %1, %1, %3\n\t"
    "s_nop 0\n\t"
    "v_mov_b32_dpp %2, %0 row_half_mirror row_mask:0xf bank_mask:0xf\n\t"
    "v_mov_b32_dpp %3, %1 row_half_mirror row_mask:0xf bank_mask:0xf\n\t"
    "s_nop 0\n\t"
    "v_add_f32 %0, %0, %2\n\t"
    "v_add_f32 %1, %1, %3\n\t"
    "s_nop 0\n\t"
    "v_mov_b32_dpp %2, %0 row_mirror row_mask:0xf bank_mask:0xf\n\t"
    "v_mov_b32_dpp %3, %1 row_mirror row_mask:0xf bank_mask:0xf\n\t"
    "s_nop 0\n\t"
    "v_add_f32 %0, %0, %2\n\t"
    "v_add_f32 %1, %1, %3"
    : "+v"(a), "+v"(b), "=&v"(t0), "=&v"(t1));
}

__device__ __forceinline__ float dot4(const f32x4& x, const f32x4& y) {
  return fmaf(x[3], y[3], fmaf(x[2], y[2], fmaf(x[1], y[1], x[0] * y[0])));
}

__device__ __forceinline__ void gload_lds(const float* g, const float* l) {
  __builtin_amdgcn_global_load_lds((const AS1 unsigned*)g, (AS3 unsigned*)l, 4, 0, 0);
}

__global__ __launch_bounds__(64, 1)
void wkv7_scan(const float* __restrict__ R, const float* __restrict__ EW,
               const float* __restrict__ K, const float* __restrict__ V,
               const float* __restrict__ A, const float* __restrict__ B,
               const float* __restrict__ S0, float* __restrict__ X,
               float* __restrict__ SOUT)
{
  // 8 slots x (5 vectors + v) x 64 floats = 3072 floats = 12 KB
  __shared__ float smem[3072];

  const int blk = blockIdx.x;          // 0..1023
  const int xcd = blk & 7;
  const int m   = blk >> 3;            // 0..127
  const int h   = xcd * 8 + (m & 7);   // head 0..63
  const int br  = m >> 3;              // row block 0..15

  const int lane = threadIdx.x;        // 0..63
  const int cg   = lane & 15;          // cols [cg*4, cg*4+4)
  const int rl   = lane >> 4;          // local row 0..3
  const int row  = br * 4 + rl;        // 0..63
  const int c0   = cg * 4;

  const int laneoff = h * DD + lane;   // per-lane global offset, all 6 arrays

  const unsigned lb  = (unsigned)(uintptr_t)(AS3 float*)&smem[0];
  const unsigned vab = lb + (unsigned)(cg * 16);   // vector-read base
  const unsigned vvb = lb + (unsigned)(row * 4);   // v-read base (offset:1280)

  const int voffb = (h * DD + row) * 4;   // byte offset of (h,row) in one step

  f32x4 s;
  {
    const f32x4* sp = (const f32x4*)(S0 + (size_t)h * DD * DD + row * DD + c0);
    s = *sp;
  }

  auto stage = [&](int tt, int slot) {
    const size_t o = (size_t)tt * HD + laneoff;
    const float* l = &smem[slot * 384];
    gload_lds(R  + o, l);
    gload_lds(EW + o, l + 64);
    gload_lds(K  + o, l + 128);
    gload_lds(A  + o, l + 192);
    gload_lds(B  + o, l + 256);
    gload_lds(V  + o, l + 320);
  };

  auto lds_read = [&](Buf& d, int slot) {
    unsigned va = vab + (unsigned)(slot * 1536);
    unsigned vv = vvb + (unsigned)(slot * 1536);
    asm volatile(
      "ds_read_b128 %0, %6\n\t"
      "ds_read_b128 %1, %6 offset:256\n\t"
      "ds_read_b128 %2, %6 offset:512\n\t"
      "ds_read_b128 %3, %6 offset:768\n\t"
      "ds_read_b128 %4, %6 offset:1024\n\t"
      "ds_read_b32  %5, %7 offset:1280"
      : "=&v"(d.r), "=&v"(d.e), "=&v"(d.k), "=&v"(d.a), "=&v"(d.b), "=&v"(d.vv)
      : "v"(va), "v"(vv) : "memory");
  };

  auto wait_nx1 = [&](Buf& d) {
    asm volatile("s_waitcnt lgkmcnt(6)"
                 : "+v"(d.r), "+v"(d.e), "+v"(d.k), "+v"(d.a), "+v"(d.b),
                   "+v"(d.vv));
  };

  float sa;                 // sa_t = S_{t-1} . a_t, ready at body t entry
  float yprev = 0.0f;       // y_{t-1}, stored at body t
  int   yoff_prev = 2047 * (HD * 4) + voffb;  // body-0 dummy store target,
                                              // overwritten by the epilogue

  auto body = [&](Buf& cur, Buf& nx1, Buf& nx2, int t) {
    // stage t+2 resident: >=30 newer vmem ops (5 bodies x (6 loads+1 store)).
    asm volatile("s_waitcnt vmcnt(30)" ::: "memory");
    lds_read(nx2, (t + 2) & 7);
    wait_nx1(nx1);

    // ---- state update for step t (sa ready since last body) ----
    const float vv = cur.vv;
    s[0] = fmaf(cur.e[0], s[0], fmaf(sa, cur.b[0], vv * cur.k[0]));
    s[1] = fmaf(cur.e[1], s[1], fmaf(sa, cur.b[1], vv * cur.k[1]));
    s[2] = fmaf(cur.e[2], s[2], fmaf(sa, cur.b[2], vv * cur.k[2]));
    s[3] = fmaf(cur.e[3], s[3], fmaf(sa, cur.b[3], vv * cur.k[3]));

    // ---- both dots (partials) ----
    float q  = dot4(s, nx1.a);   // -> sa_{t+1}
    float yd = dot4(s, cur.r);   // -> y_t

    // ---- independent work while dots complete ----
    if (cg == 0) {
      asm volatile("global_store_dword %0, %1, %2"
                   :: "v"(yoff_prev), "v"(yprev), "s"(X) : "memory");
    }
    stage((t + 8) & (T_LEN - 1), t & 7);

    // ---- interleaved dual reduction ----
    duo_reduce(q, yd);
    sa = q;
    yprev = yd;
    yoff_prev = t * (HD * 4) + voffb;
  };

  // Prologue: fill ring (issue order = count order).
  for (int i = 0; i < 8; ++i) {
    stage(i, i);
    __builtin_amdgcn_sched_barrier(0);
  }
  asm volatile("s_waitcnt vmcnt(36)" ::: "memory");  // stages 0,1 done

  Buf B0, B1, B2, B3;
  lds_read(B0, 0);
  lds_read(B1, 1);
  asm volatile("s_waitcnt lgkmcnt(0)"
               : "+v"(B0.r), "+v"(B0.e), "+v"(B0.k), "+v"(B0.a), "+v"(B0.b),
                 "+v"(B0.vv), "+v"(B1.a));

  // sa_0 = S_init . a_0 (prologue pays one serial reduce)
  sa = row16_reduce(dot4(s, B0.a));

  for (int t = 0; t < T_LEN; t += 4) {
    body(B0, B1, B2, t);
    body(B1, B2, B3, t + 1);
    body(B2, B3, B0, t + 2);
    body(B3, B0, B1, t + 3);
  }

  // Epilogue: final y (t = 2047) — also overwrites body-0's dummy store.
  if (cg == 0) {
    asm volatile("global_store_dword %0, %1, %2"
                 :: "v"(yoff_prev), "v"(yprev), "s"(X) : "memory");
  }

  *(f32x4*)(SOUT + (size_t)h * DD * DD + row * DD + c0) = s;
}

extern "C" void kernel_launch(void* const* d_in, const int* in_sizes, int n_in,
                              void* d_out, int out_size, void* d_ws, size_t ws_size,
                              hipStream_t stream) {
  // setup_inputs order: seq_length, r, w, k, v, a, b, state2
  const float* r  = (const float*)d_in[1];
  const float* w  = (const float*)d_in[2];
  const float* k  = (const float*)d_in[3];
  const float* v  = (const float*)d_in[4];
  const float* a  = (const float*)d_in[5];
  const float* b  = (const float*)d_in[6];
  const float* s0 = (const float*)d_in[7];

  float* x    = (float*)d_out;                     // (T, H, 1, D)
  float* sout = x + (size_t)T_LEN * HD;            // (H, D, D)

  float* ew = (float*)d_ws;
  (void)ws_size; (void)in_sizes; (void)n_in;

  int n4 = T_LEN * HD / 4;
  hipLaunchKernelGGL(exp_kernel, dim3(1024), dim3(256), 0, stream,
                     (const float4*)w, (float4*)ew, n4);
  hipLaunchKernelGGL(wkv7_scan, dim3(1024), dim3(64), 0, stream,
                     r, ew, k, v, a, b, s0, x, sout);
}